// Round 2
// baseline (40466.989 us; speedup 1.0000x reference)
//
#include <hip/hip_runtime.h>

typedef __attribute__((ext_vector_type(8))) short short8;
typedef __attribute__((ext_vector_type(4))) float float4_t;
typedef __attribute__((ext_vector_type(2))) float float2_t;
typedef unsigned short u16;
typedef unsigned int u32;

// B=256, T=256, IN=128, S=1024
// phases p=0..511: t=p>>1, stage=p&1

__device__ __forceinline__ u16 f2bf(float f) {
  u32 u = __builtin_bit_cast(u32, f);
  u += 0x7fffu + ((u >> 16) & 1u);          // RNE
  return (u16)(u >> 16);
}
__device__ __forceinline__ float bf2f(u16 h) {
  u32 u = ((u32)h) << 16;
  return __builtin_bit_cast(float, u);
}
__device__ __forceinline__ short8 cvt8(float4_t f0, float4_t f1) {
  short8 v;
  v[0]=(short)f2bf(f0[0]); v[1]=(short)f2bf(f0[1]); v[2]=(short)f2bf(f0[2]); v[3]=(short)f2bf(f0[3]);
  v[4]=(short)f2bf(f1[0]); v[5]=(short)f2bf(f1[1]); v[6]=(short)f2bf(f1[2]); v[7]=(short)f2bf(f1[3]);
  return v;
}

__global__ __launch_bounds__(64) void init_counter(u32* __restrict__ cnt) {
  if (threadIdx.x < 16) cnt[threadIdx.x] = 0u;
}

__global__ __launch_bounds__(256) void prep_w(const float* __restrict__ Wr,
                                              const float* __restrict__ Wr2,
                                              u16* __restrict__ W1b,
                                              u16* __restrict__ W2b) {
  const int i = blockIdx.x * 256 + threadIdx.x;   // 0 .. 1048575
  W1b[i] = f2bf(Wr[i]);
  W2b[i] = f2bf(Wr2[i]);
}

// ext GEMM: ebuf[t][b][n] = sum_k x[b][t][k]*Win[n][k] + bin[n], bf16 out.
// M=65536 (row m = b*256+t), N=1024, K=128. Tile 64x64, 4 waves (one 16-row slice each).
__global__ __launch_bounds__(256) void ext_gemm(const float* __restrict__ x,
                                                const float* __restrict__ Win,
                                                const float* __restrict__ bin,
                                                u16* __restrict__ ebuf) {
  const int wg = blockIdx.x;
  const int nt = wg & 15, mt = wg >> 4;           // mt 0..1023
  const int tid = threadIdx.x;
  const int wave = tid >> 6, lane = tid & 63, quad = lane >> 4, lm = lane & 15;
  const int m0 = (mt << 6) + (wave << 4);
  const int n0 = nt << 6;

  short8 a[4];
#pragma unroll
  for (int ks = 0; ks < 4; ++ks) {
    const float* p = x + (m0 + lm) * 128 + (ks * 32 + quad * 8);
    a[ks] = cvt8(*(const float4_t*)p, *(const float4_t*)(p + 4));
  }
  short8 bfr[4][4];
#pragma unroll
  for (int nsub = 0; nsub < 4; ++nsub)
#pragma unroll
    for (int ks = 0; ks < 4; ++ks) {
      const float* p = Win + (n0 + (nsub << 4) + lm) * 128 + (ks * 32 + quad * 8);
      bfr[nsub][ks] = cvt8(*(const float4_t*)p, *(const float4_t*)(p + 4));
    }
  float4_t acc[4] = { {0,0,0,0},{0,0,0,0},{0,0,0,0},{0,0,0,0} };
#pragma unroll
  for (int ks = 0; ks < 4; ++ks)
#pragma unroll
    for (int nsub = 0; nsub < 4; ++nsub)
      acc[nsub] = __builtin_amdgcn_mfma_f32_16x16x32_bf16(a[ks], bfr[nsub][ks], acc[nsub], 0, 0, 0);

#pragma unroll
  for (int nsub = 0; nsub < 4; ++nsub) {
    const int n = n0 + (nsub << 4) + lm;
    const float bv = bin[n];
#pragma unroll
    for (int r = 0; r < 4; ++r) {
      const int m = m0 + (quad << 2) + r;
      const int b = m >> 8, t = m & 255;
      ebuf[(((t << 8) | b) << 10) + n] = f2bf(acc[nsub][r] + bv);
    }
  }
}

// Persistent recurrence. Grid 256 WGs x 512 thr (8 waves). WG = (mt 0..15: 16 batch rows,
// ns 0..15: 64 output cols). Waves 0-3: W_rec (k-quarters 0-3); waves 4-7: W_rec2.
// Weights stay in VGPRs (32 x uint4 = 128 VGPRs per wave) for all 512 phases.
__global__ __launch_bounds__(512, 2) void rnn_persistent(
    const u16* __restrict__ ebuf, u16* __restrict__ buf0, u16* __restrict__ buf1,
    const u16* __restrict__ W1b, const u16* __restrict__ W2b,
    const float* __restrict__ b1, const float* __restrict__ b2,
    float* __restrict__ fbuf, u32* __restrict__ cnt) {
  __shared__ __align__(16) u16 At[16 * 1032];      // A tile, 1032-elem row stride (pad)
  __shared__ __align__(16) float Pt[4][16][68];    // k-split partials [q][m][n(+pad)]

  const int tid = threadIdx.x;
  const int wave = tid >> 6, lane = tid & 63, quad = lane >> 4, lm = lane & 15;
  const int mt = blockIdx.x >> 4, ns = blockIdx.x & 15;
  const int n0 = ns << 6;
  const int mat = wave >> 2, q = wave & 3;

  // persistent weight fragments: B[k][n], lane: n=lm, k=quad*8+j (within 32-k slice)
  short8 wfrag[4][8];
  {
    const u16* Wm = mat ? W2b : W1b;
#pragma unroll
    for (int nsub = 0; nsub < 4; ++nsub)
#pragma unroll
      for (int ks = 0; ks < 8; ++ks)
        wfrag[nsub][ks] = __builtin_bit_cast(short8,
            *(const uint4*)(Wm + ((n0 + (nsub << 4) + lm) << 10) + (q << 8) + (ks << 5) + (quad << 3)));
  }

  const int srow = tid >> 5;             // staging: 16 rows, 32 thr/row
  const int scol = (tid & 31) << 6;      // byte col 0..2032 step 64
  const int me = tid >> 5;               // epilogue row 0..15
  const int nc = (tid & 31) << 1;        // epilogue col base (2 cols, 0..62)
  const u32 nwg = gridDim.x;             // 256

  for (int p = 0; p < 512; ++p) {
    const int t = p >> 1, st = p & 1;

    if (p) {  // grid barrier: wait for all WGs to finish phase p-1
      if (tid == 0) {
        const u32 target = (u32)p * nwg;
        while (__hip_atomic_load(cnt, __ATOMIC_RELAXED, __HIP_MEMORY_SCOPE_AGENT) < target)
          __builtin_amdgcn_s_sleep(1);
      }
      __syncthreads();
      __threadfence();   // acquire: invalidate stale cached state
    }

    const u16* uIn = st ? buf1 : (t == 0 ? ebuf : buf0);

    // prefetch e(t+1) early (consumed in stage-2 epilogue): 2 cols per thread
    u32 e2 = 0;
    if (st && t < 255)
      e2 = *(const u32*)(ebuf + ((((t + 1) << 8) + (mt << 4) + me) << 10) + n0 + nc);

    // stage A tile [16 x 1024] bf16 into LDS (all 8 waves)
    {
      const char* src = (const char*)uIn + (((mt << 4) + srow) << 11) + scol;
      char* dst = (char*)At + srow * 2064 + scol;
#pragma unroll
      for (int i = 0; i < 4; ++i)
        *(uint4*)(dst + (i << 4)) = *(const uint4*)(src + (i << 4));
    }
    __syncthreads();

    if (mat == st) {  // active waves for this stage
      float4_t acc[4] = { {0,0,0,0},{0,0,0,0},{0,0,0,0},{0,0,0,0} };
#pragma unroll
      for (int ks = 0; ks < 8; ++ks) {
        const short8 a = __builtin_bit_cast(short8,
            *(const uint4*)((const char*)At + lm * 2064 + (q << 9) + (ks << 6) + (quad << 4)));
#pragma unroll
        for (int nsub = 0; nsub < 4; ++nsub)
          acc[nsub] = __builtin_amdgcn_mfma_f32_16x16x32_bf16(a, wfrag[nsub][ks], acc[nsub], 0, 0, 0);
      }
#pragma unroll
      for (int nsub = 0; nsub < 4; ++nsub)
#pragma unroll
        for (int r = 0; r < 4; ++r)
          Pt[q][(quad << 2) + r][(nsub << 4) + lm] = acc[nsub][r];
    }
    __syncthreads();

    // epilogue: reduce k-split, bias, relu, (+e for stage2), store.
    // 512 threads x 2 elements = 16 rows x 64 cols.
    {
      const float2_t p0 = *(const float2_t*)&Pt[0][me][nc];
      const float2_t p1 = *(const float2_t*)&Pt[1][me][nc];
      const float2_t p2 = *(const float2_t*)&Pt[2][me][nc];
      const float2_t p3 = *(const float2_t*)&Pt[3][me][nc];
      const float* bv = st ? b2 : b1;
      const float2_t bias = *(const float2_t*)(bv + n0 + nc);
      float2_t s = p0 + p1 + p2 + p3 + bias;
      s[0] = s[0] > 0.f ? s[0] : 0.f;
      s[1] = s[1] > 0.f ? s[1] : 0.f;
      const int gr = (mt << 4) + me;
      if (!st) {
        u32 o = (u32)f2bf(s[0]) | ((u32)f2bf(s[1]) << 16);
        *(u32*)(buf1 + (gr << 10) + n0 + nc) = o;
      } else if (t < 255) {
        s[0] += bf2f((u16)(e2 & 0xffffu));
        s[1] += bf2f((u16)(e2 >> 16));
        u32 o = (u32)f2bf(s[0]) | ((u32)f2bf(s[1]) << 16);
        *(u32*)(buf0 + (gr << 10) + n0 + nc) = o;
      } else {
        *(float2_t*)(fbuf + (gr << 10) + n0 + nc) = s;  // final state, fp32
      }
    }

    // arrive
    __threadfence();   // release: make stores visible device-wide
    __syncthreads();
    if (tid == 0)
      __hip_atomic_fetch_add(cnt, 1u, __ATOMIC_RELEASE, __HIP_MEMORY_SCOPE_AGENT);
  }
}

__global__ __launch_bounds__(256) void bcast(const float* __restrict__ fbuf,
                                             float* __restrict__ out) {
  const int idx4 = blockIdx.x * 256 + threadIdx.x;   // 0..16777215 float4s
  const int b = idx4 >> 16;
  const int s4 = idx4 & 255;
  const float4_t v = *(const float4_t*)(fbuf + (b << 10) + (s4 << 2));
  *(float4_t*)(out + ((size_t)idx4 << 2)) = v;
}

extern "C" void kernel_launch(void* const* d_in, const int* in_sizes, int n_in,
                              void* d_out, int out_size, void* d_ws, size_t ws_size,
                              hipStream_t stream) {
  const float* x     = (const float*)d_in[0];
  const float* Win   = (const float*)d_in[1];
  const float* bin   = (const float*)d_in[2];
  const float* Wrec  = (const float*)d_in[3];
  const float* brec  = (const float*)d_in[4];
  const float* Wrec2 = (const float*)d_in[5];
  const float* brec2 = (const float*)d_in[6];
  float* out = (float*)d_out;

  char* ws = (char*)d_ws;
  u16* W1b  = (u16*)(ws);                               // 2 MB
  u16* W2b  = (u16*)(ws + (2u << 20));                  // 2 MB
  u16* buf0 = (u16*)(ws + (4u << 20));                  // 512 KB
  u16* buf1 = (u16*)(ws + (4u << 20) + (512u << 10));   // 512 KB
  float* fbuf = (float*)(ws + (5u << 20));              // 1 MB
  u32* cnt  = (u32*)(ws + (6u << 20));                  // 64 B
  u16* ebuf = (u16*)d_out;  // 128 MB scratch inside out (268 MB); dead before bcast

  init_counter<<<1, 64, 0, stream>>>(cnt);
  prep_w<<<4096, 256, 0, stream>>>(Wrec, Wrec2, W1b, W2b);
  ext_gemm<<<16384, 256, 0, stream>>>(x, Win, bin, ebuf);

  void* args[] = { (void*)&ebuf, (void*)&buf0, (void*)&buf1, (void*)&W1b, (void*)&W2b,
                   (void*)&brec, (void*)&brec2, (void*)&fbuf, (void*)&cnt };
  (void)hipLaunchCooperativeKernel(reinterpret_cast<void*>(rnn_persistent),
                                   dim3(256), dim3(512), args, 0, stream);

  bcast<<<65536, 256, 0, stream>>>(fbuf, out);
}

// Round 3
// 3290.960 us; speedup vs baseline: 12.2964x; 12.2964x over previous
//
#include <hip/hip_runtime.h>

typedef __attribute__((ext_vector_type(8))) short short8;
typedef __attribute__((ext_vector_type(4))) float float4_t;
typedef __attribute__((ext_vector_type(2))) float float2_t;
typedef unsigned short u16;
typedef unsigned int u32;
typedef unsigned long long u64;

// B=256, T=256, IN=128, S=1024
// phases p=0..511: t=p>>1, stage=p&1

__device__ __forceinline__ u16 f2bf(float f) {
  u32 u = __builtin_bit_cast(u32, f);
  u += 0x7fffu + ((u >> 16) & 1u);          // RNE
  return (u16)(u >> 16);
}
__device__ __forceinline__ float bf2f(u16 h) {
  u32 u = ((u32)h) << 16;
  return __builtin_bit_cast(float, u);
}
__device__ __forceinline__ short8 cvt8(float4_t f0, float4_t f1) {
  short8 v;
  v[0]=(short)f2bf(f0[0]); v[1]=(short)f2bf(f0[1]); v[2]=(short)f2bf(f0[2]); v[3]=(short)f2bf(f0[3]);
  v[4]=(short)f2bf(f1[0]); v[5]=(short)f2bf(f1[1]); v[6]=(short)f2bf(f1[2]); v[7]=(short)f2bf(f1[3]);
  return v;
}

__global__ __launch_bounds__(256) void init_counter(u32* __restrict__ cnt) {
  cnt[threadIdx.x] = 0u;
  cnt[256 + threadIdx.x] = 0u;
  cnt[512 + threadIdx.x] = 0u;
  cnt[768 + threadIdx.x] = 0u;
}

__global__ __launch_bounds__(256) void prep_w(const float* __restrict__ Wr,
                                              const float* __restrict__ Wr2,
                                              u16* __restrict__ W1b,
                                              u16* __restrict__ W2b) {
  const int i = blockIdx.x * 256 + threadIdx.x;   // 0 .. 1048575
  W1b[i] = f2bf(Wr[i]);
  W2b[i] = f2bf(Wr2[i]);
}

// ext GEMM: ebuf[t][b][n] = sum_k x[b][t][k]*Win[n][k] + bin[n], bf16 out.
__global__ __launch_bounds__(256) void ext_gemm(const float* __restrict__ x,
                                                const float* __restrict__ Win,
                                                const float* __restrict__ bin,
                                                u16* __restrict__ ebuf) {
  const int wg = blockIdx.x;
  const int nt = wg & 15, mt = wg >> 4;           // mt 0..1023
  const int tid = threadIdx.x;
  const int wave = tid >> 6, lane = tid & 63, quad = lane >> 4, lm = lane & 15;
  const int m0 = (mt << 6) + (wave << 4);
  const int n0 = nt << 6;

  short8 a[4];
#pragma unroll
  for (int ks = 0; ks < 4; ++ks) {
    const float* p = x + (m0 + lm) * 128 + (ks * 32 + quad * 8);
    a[ks] = cvt8(*(const float4_t*)p, *(const float4_t*)(p + 4));
  }
  short8 bfr[4][4];
#pragma unroll
  for (int nsub = 0; nsub < 4; ++nsub)
#pragma unroll
    for (int ks = 0; ks < 4; ++ks) {
      const float* p = Win + (n0 + (nsub << 4) + lm) * 128 + (ks * 32 + quad * 8);
      bfr[nsub][ks] = cvt8(*(const float4_t*)p, *(const float4_t*)(p + 4));
    }
  float4_t acc[4] = { {0,0,0,0},{0,0,0,0},{0,0,0,0},{0,0,0,0} };
#pragma unroll
  for (int ks = 0; ks < 4; ++ks)
#pragma unroll
    for (int nsub = 0; nsub < 4; ++nsub)
      acc[nsub] = __builtin_amdgcn_mfma_f32_16x16x32_bf16(a[ks], bfr[nsub][ks], acc[nsub], 0, 0, 0);

#pragma unroll
  for (int nsub = 0; nsub < 4; ++nsub) {
    const int n = n0 + (nsub << 4) + lm;
    const float bv = bin[n];
#pragma unroll
    for (int r = 0; r < 4; ++r) {
      const int m = m0 + (quad << 2) + r;
      const int b = m >> 8, t = m & 255;
      ebuf[(((t << 8) | b) << 10) + n] = f2bf(acc[nsub][r] + bv);
    }
  }
}

// Persistent recurrence. 256 WGs x 512 thr (8 waves). WG = (mt: 16 batch rows, ns: 64 cols).
// Waves 0-3: W_rec (k-quarters); waves 4-7: W_rec2. Weights live in VGPRs for all 512 phases.
// Coherence: buf0/buf1 accessed ONLY via agent-scope relaxed atomics (sc1 -> bypass the
// non-coherent per-XCD L2). NO __threadfence (no L2 writeback/invalidate walks).
// Barrier: 8 padded arrival counters (32 WGs each, relaxed RMW after explicit vmcnt drain);
// WG0 detects and broadcasts a read-only flag; everyone polls the flag line only.
__global__ __launch_bounds__(512, 2) void rnn_persistent(
    const u16* __restrict__ ebuf, u16* __restrict__ buf0, u16* __restrict__ buf1,
    const u16* __restrict__ W1b, const u16* __restrict__ W2b,
    const float* __restrict__ b1, const float* __restrict__ b2,
    float* __restrict__ fbuf, u32* __restrict__ cnt) {
  __shared__ __align__(16) u16 At[16 * 1032];      // A tile, padded row stride (2064 B)
  __shared__ __align__(16) float Pt[4][16][68];    // k-split partials [q][m][n(+pad)]

  const int tid = threadIdx.x;
  const int wave = tid >> 6, lane = tid & 63, quad = lane >> 4, lm = lane & 15;
  const int mt = blockIdx.x >> 4, ns = blockIdx.x & 15;
  const int n0 = ns << 6;
  const int mat = wave >> 2, q = wave & 3;

  // persistent weight fragments: B[k][n], lane: n=lm, k=quad*8+j (within 32-k slice)
  short8 wfrag[4][8];
  {
    const u16* Wm = mat ? W2b : W1b;
#pragma unroll
    for (int nsub = 0; nsub < 4; ++nsub)
#pragma unroll
      for (int ks = 0; ks < 8; ++ks)
        wfrag[nsub][ks] = __builtin_bit_cast(short8,
            *(const uint4*)(Wm + ((n0 + (nsub << 4) + lm) << 10) + (q << 8) + (ks << 5) + (quad << 3)));
  }

  const int srow = tid >> 5;             // staging: 16 rows, 32 thr/row
  const int sc16 = (tid & 31) << 5;      // u16 col base, 32 elems (64 B) per thread
  const int me = tid >> 5;               // epilogue row 0..15
  const int nc = (tid & 31) << 1;        // epilogue col base (2 cols)

  u32* arr = cnt + ((blockIdx.x & 7) << 6);   // this WG's arrival counter (256 B apart)
  u32* flag = cnt + 512;                      // phase-complete broadcast flag

  for (int p = 0; p < 512; ++p) {
    const int t = p >> 1, st = p & 1;

    // prefetch e(t+1) (read-only ebuf, consumed in stage-2 epilogue) — overlaps the wait
    u32 e2 = 0;
    if (st && t < 255)
      e2 = *(const u32*)(ebuf + ((((t + 1) << 8) + (mt << 4) + me) << 10) + n0 + nc);

    if (p) {  // wait for phase p-1 completion
      if (blockIdx.x == 0 && tid < 8) {
        const u32 tgt = (u32)p * 32u;
        while (__hip_atomic_load(cnt + (tid << 6), __ATOMIC_RELAXED, __HIP_MEMORY_SCOPE_AGENT) < tgt)
          __builtin_amdgcn_s_sleep(1);
        if (tid == 0)
          __hip_atomic_store(flag, (u32)p, __ATOMIC_RELAXED, __HIP_MEMORY_SCOPE_AGENT);
      }
      if (tid == 0) {
        while (__hip_atomic_load(flag, __ATOMIC_RELAXED, __HIP_MEMORY_SCOPE_AGENT) < (u32)p)
          __builtin_amdgcn_s_sleep(2);
      }
      __syncthreads();
    }

    const u16* uIn = st ? buf1 : (t == 0 ? ebuf : buf0);

    // stage A tile [16 x 1024] bf16 into LDS via agent-coherent loads (sc1, L2-bypass)
    {
      const u64* src = (const u64*)(uIn + (((mt << 4) + srow) << 10) + sc16);
      u64* dst = (u64*)((char*)At + srow * 2064 + (sc16 << 1));
      u64 v[8];
#pragma unroll
      for (int i = 0; i < 8; ++i)
        v[i] = __hip_atomic_load(src + i, __ATOMIC_RELAXED, __HIP_MEMORY_SCOPE_AGENT);
#pragma unroll
      for (int i = 0; i < 8; ++i) dst[i] = v[i];
    }
    __syncthreads();

    if (mat == st) {  // active waves for this stage
      float4_t acc[4] = { {0,0,0,0},{0,0,0,0},{0,0,0,0},{0,0,0,0} };
#pragma unroll
      for (int ks = 0; ks < 8; ++ks) {
        const short8 a = __builtin_bit_cast(short8,
            *(const uint4*)((const char*)At + lm * 2064 + (q << 9) + (ks << 6) + (quad << 4)));
#pragma unroll
        for (int nsub = 0; nsub < 4; ++nsub)
          acc[nsub] = __builtin_amdgcn_mfma_f32_16x16x32_bf16(a, wfrag[nsub][ks], acc[nsub], 0, 0, 0);
      }
#pragma unroll
      for (int nsub = 0; nsub < 4; ++nsub)
#pragma unroll
        for (int r = 0; r < 4; ++r)
          Pt[q][(quad << 2) + r][(nsub << 4) + lm] = acc[nsub][r];
    }
    __syncthreads();

    // epilogue: reduce k-split, bias, relu, (+e for stage2), store (512 thr x 2 elems)
    {
      const float2_t p0 = *(const float2_t*)&Pt[0][me][nc];
      const float2_t p1 = *(const float2_t*)&Pt[1][me][nc];
      const float2_t p2 = *(const float2_t*)&Pt[2][me][nc];
      const float2_t p3 = *(const float2_t*)&Pt[3][me][nc];
      const float* bv = st ? b2 : b1;
      const float2_t bias = *(const float2_t*)(bv + n0 + nc);
      float2_t s = p0 + p1 + p2 + p3 + bias;
      s[0] = s[0] > 0.f ? s[0] : 0.f;
      s[1] = s[1] > 0.f ? s[1] : 0.f;
      const int gr = (mt << 4) + me;
      if (!st) {
        u32 o = (u32)f2bf(s[0]) | ((u32)f2bf(s[1]) << 16);
        __hip_atomic_store((u32*)(buf1 + (gr << 10) + n0 + nc), o,
                           __ATOMIC_RELAXED, __HIP_MEMORY_SCOPE_AGENT);
      } else if (t < 255) {
        s[0] += bf2f((u16)(e2 & 0xffffu));
        s[1] += bf2f((u16)(e2 >> 16));
        u32 o = (u32)f2bf(s[0]) | ((u32)f2bf(s[1]) << 16);
        __hip_atomic_store((u32*)(buf0 + (gr << 10) + n0 + nc), o,
                           __ATOMIC_RELAXED, __HIP_MEMORY_SCOPE_AGENT);
      } else {
        *(float2_t*)(fbuf + (gr << 10) + n0 + nc) = s;  // final state; kernel-end flush
      }
    }

    // arrive: drain coherent stores to the coherence point, then relaxed RMW
    if (p < 511) {
      asm volatile("s_waitcnt vmcnt(0)" ::: "memory");
      __syncthreads();
      if (tid == 0)
        __hip_atomic_fetch_add(arr, 1u, __ATOMIC_RELAXED, __HIP_MEMORY_SCOPE_AGENT);
    }
  }
}

__global__ __launch_bounds__(256) void bcast(const float* __restrict__ fbuf,
                                             float* __restrict__ out) {
  const int idx4 = blockIdx.x * 256 + threadIdx.x;   // 0..16777215 float4s
  const int b = idx4 >> 16;
  const int s4 = idx4 & 255;
  const float4_t v = *(const float4_t*)(fbuf + (b << 10) + (s4 << 2));
  *(float4_t*)(out + ((size_t)idx4 << 2)) = v;
}

extern "C" void kernel_launch(void* const* d_in, const int* in_sizes, int n_in,
                              void* d_out, int out_size, void* d_ws, size_t ws_size,
                              hipStream_t stream) {
  const float* x     = (const float*)d_in[0];
  const float* Win   = (const float*)d_in[1];
  const float* bin   = (const float*)d_in[2];
  const float* Wrec  = (const float*)d_in[3];
  const float* brec  = (const float*)d_in[4];
  const float* Wrec2 = (const float*)d_in[5];
  const float* brec2 = (const float*)d_in[6];
  float* out = (float*)d_out;

  char* ws = (char*)d_ws;
  u16* W1b  = (u16*)(ws);                               // 2 MB
  u16* W2b  = (u16*)(ws + (2u << 20));                  // 2 MB
  u16* buf0 = (u16*)(ws + (4u << 20));                  // 512 KB
  u16* buf1 = (u16*)(ws + (4u << 20) + (512u << 10));   // 512 KB
  float* fbuf = (float*)(ws + (5u << 20));              // 1 MB
  u32* cnt  = (u32*)(ws + (6u << 20));                  // 4 KB (8 counters + flag)
  u16* ebuf = (u16*)d_out;  // 128 MB scratch inside out (268 MB); dead before bcast

  init_counter<<<1, 256, 0, stream>>>(cnt);
  prep_w<<<4096, 256, 0, stream>>>(Wrec, Wrec2, W1b, W2b);
  ext_gemm<<<16384, 256, 0, stream>>>(x, Win, bin, ebuf);

  void* args[] = { (void*)&ebuf, (void*)&buf0, (void*)&buf1, (void*)&W1b, (void*)&W2b,
                   (void*)&brec, (void*)&brec2, (void*)&fbuf, (void*)&cnt };
  (void)hipLaunchCooperativeKernel(reinterpret_cast<void*>(rnn_persistent),
                                   dim3(256), dim3(512), args, 0, stream);

  bcast<<<65536, 256, 0, stream>>>(fbuf, out);
}

// Round 4
// 2473.576 us; speedup vs baseline: 16.3597x; 1.3304x over previous
//
#include <hip/hip_runtime.h>

typedef __attribute__((ext_vector_type(8))) short short8;
typedef __attribute__((ext_vector_type(4))) float float4_t;
typedef __attribute__((ext_vector_type(2))) float float2_t;
typedef __attribute__((ext_vector_type(2))) unsigned long long u64x2;
typedef unsigned short u16;
typedef unsigned int u32;
typedef unsigned long long u64;

// B=256, T=256, IN=128, S=1024
// phases p=0..511: t=p>>1, stage=p&1

__device__ __forceinline__ u16 f2bf(float f) {
  u32 u = __builtin_bit_cast(u32, f);
  u += 0x7fffu + ((u >> 16) & 1u);          // RNE
  return (u16)(u >> 16);
}
__device__ __forceinline__ float bf2f(u16 h) {
  u32 u = ((u32)h) << 16;
  return __builtin_bit_cast(float, u);
}
__device__ __forceinline__ short8 cvt8(float4_t f0, float4_t f1) {
  short8 v;
  v[0]=(short)f2bf(f0[0]); v[1]=(short)f2bf(f0[1]); v[2]=(short)f2bf(f0[2]); v[3]=(short)f2bf(f0[3]);
  v[4]=(short)f2bf(f1[0]); v[5]=(short)f2bf(f1[1]); v[6]=(short)f2bf(f1[2]); v[7]=(short)f2bf(f1[3]);
  return v;
}

__global__ __launch_bounds__(256) void init_counter(u32* __restrict__ cnt) {
  cnt[threadIdx.x] = 0u;
  cnt[256 + threadIdx.x] = 0u;
  cnt[512 + threadIdx.x] = 0u;
  cnt[768 + threadIdx.x] = 0u;
}

__global__ __launch_bounds__(256) void prep_w(const float* __restrict__ Wr,
                                              const float* __restrict__ Wr2,
                                              u16* __restrict__ W1b,
                                              u16* __restrict__ W2b) {
  const int i = blockIdx.x * 256 + threadIdx.x;   // 0 .. 1048575
  W1b[i] = f2bf(Wr[i]);
  W2b[i] = f2bf(Wr2[i]);
}

// ext GEMM: ebuf[t][b][n] = sum_k x[b][t][k]*Win[n][k] + bin[n], bf16 out.
__global__ __launch_bounds__(256) void ext_gemm(const float* __restrict__ x,
                                                const float* __restrict__ Win,
                                                const float* __restrict__ bin,
                                                u16* __restrict__ ebuf) {
  const int wg = blockIdx.x;
  const int nt = wg & 15, mt = wg >> 4;           // mt 0..1023
  const int tid = threadIdx.x;
  const int wave = tid >> 6, lane = tid & 63, quad = lane >> 4, lm = lane & 15;
  const int m0 = (mt << 6) + (wave << 4);
  const int n0 = nt << 6;

  short8 a[4];
#pragma unroll
  for (int ks = 0; ks < 4; ++ks) {
    const float* p = x + (m0 + lm) * 128 + (ks * 32 + quad * 8);
    a[ks] = cvt8(*(const float4_t*)p, *(const float4_t*)(p + 4));
  }
  short8 bfr[4][4];
#pragma unroll
  for (int nsub = 0; nsub < 4; ++nsub)
#pragma unroll
    for (int ks = 0; ks < 4; ++ks) {
      const float* p = Win + (n0 + (nsub << 4) + lm) * 128 + (ks * 32 + quad * 8);
      bfr[nsub][ks] = cvt8(*(const float4_t*)p, *(const float4_t*)(p + 4));
    }
  float4_t acc[4] = { {0,0,0,0},{0,0,0,0},{0,0,0,0},{0,0,0,0} };
#pragma unroll
  for (int ks = 0; ks < 4; ++ks)
#pragma unroll
    for (int nsub = 0; nsub < 4; ++nsub)
      acc[nsub] = __builtin_amdgcn_mfma_f32_16x16x32_bf16(a[ks], bfr[nsub][ks], acc[nsub], 0, 0, 0);

#pragma unroll
  for (int nsub = 0; nsub < 4; ++nsub) {
    const int n = n0 + (nsub << 4) + lm;
    const float bv = bin[n];
#pragma unroll
    for (int r = 0; r < 4; ++r) {
      const int m = m0 + (quad << 2) + r;
      const int b = m >> 8, t = m & 255;
      ebuf[(((t << 8) | b) << 10) + n] = f2bf(acc[nsub][r] + bv);
    }
  }
}

// Persistent recurrence. 256 WGs x 512 thr (8 waves). WG = (mt: 16 batch rows, ns: 64 cols).
// Batch rows are INDEPENDENT across groups: WG (mt,ns) only exchanges data with the 16 WGs
// sharing mt. Barrier = per-group counter (16 arrivals), direct poll, no global sync.
// Waves 0-3: W_rec (k-quarters); waves 4-7: W_rec2; weights persist in VGPRs/AGPRs.
// A-fragments load straight from the coherent state buffer into registers (sc1 u64 loads)
// — no LDS staging. Only the k-split partial reduce (Pt) uses LDS.
__global__ __launch_bounds__(512, 2) void rnn_persistent(
    const u16* __restrict__ ebuf, u16* __restrict__ buf0, u16* __restrict__ buf1,
    const u16* __restrict__ W1b, const u16* __restrict__ W2b,
    const float* __restrict__ b1, const float* __restrict__ b2,
    float* __restrict__ fbuf, u32* __restrict__ cnt) {
  __shared__ __align__(16) float Pt[4][16][68];    // k-split partials [q][m][n(+pad)]

  const int tid = threadIdx.x;
  const int wave = tid >> 6, lane = tid & 63, quad = lane >> 4, lm = lane & 15;
  const int mt = blockIdx.x >> 4, ns = blockIdx.x & 15;
  const int n0 = ns << 6;
  const int mat = wave >> 2, q = wave & 3;

  // persistent weight fragments: B[k][n], lane: n=lm, k=quad*8+j (within 32-k slice)
  short8 wfrag[4][8];
  {
    const u16* Wm = mat ? W2b : W1b;
#pragma unroll
    for (int nsub = 0; nsub < 4; ++nsub)
#pragma unroll
      for (int ks = 0; ks < 8; ++ks)
        wfrag[nsub][ks] = __builtin_bit_cast(short8,
            *(const uint4*)(Wm + ((n0 + (nsub << 4) + lm) << 10) + (q << 8) + (ks << 5) + (quad << 3)));
  }

  const int me = tid >> 5;               // epilogue row 0..15
  const int nc = (tid & 31) << 1;        // epilogue col base (2 cols)

  u32* grp = cnt + (mt << 6);            // this group's barrier counter (256 B apart)

  for (int p = 0; p < 512; ++p) {
    const int t = p >> 1, st = p & 1;

    // prefetch e(t+1) (read-only ebuf, consumed in stage-2 epilogue) — overlaps the wait
    u32 e2 = 0;
    if (st && t < 255)
      e2 = *(const u32*)(ebuf + ((((t + 1) << 8) + (mt << 4) + me) << 10) + n0 + nc);

    if (p) {  // group barrier: wait for all 16 WGs of group mt to finish phase p-1
      if (tid == 0) {
        const u32 tgt = (u32)p * 16u;
        while (__hip_atomic_load(grp, __ATOMIC_RELAXED, __HIP_MEMORY_SCOPE_AGENT) < tgt)
          __builtin_amdgcn_s_sleep(1);
      }
      __syncthreads();
    }

    const u16* uIn = st ? buf1 : (t == 0 ? ebuf : buf0);

    if (mat == st) {  // active waves for this stage
      // A-fragments direct to registers: row lm of this WG's 16-row slice, k-quarter q
      u64x2 av[8];
      {
        const u16* rb = uIn + (((mt << 4) + lm) << 10) + (q << 8) + (quad << 3);
#pragma unroll
        for (int ks = 0; ks < 8; ++ks) {
          const u64* pk = (const u64*)(rb + (ks << 5));
          av[ks][0] = __hip_atomic_load(pk, __ATOMIC_RELAXED, __HIP_MEMORY_SCOPE_AGENT);
          av[ks][1] = __hip_atomic_load(pk + 1, __ATOMIC_RELAXED, __HIP_MEMORY_SCOPE_AGENT);
        }
      }
      float4_t acc[4] = { {0,0,0,0},{0,0,0,0},{0,0,0,0},{0,0,0,0} };
#pragma unroll
      for (int ks = 0; ks < 8; ++ks) {
        const short8 a = __builtin_bit_cast(short8, av[ks]);
#pragma unroll
        for (int nsub = 0; nsub < 4; ++nsub)
          acc[nsub] = __builtin_amdgcn_mfma_f32_16x16x32_bf16(a, wfrag[nsub][ks], acc[nsub], 0, 0, 0);
      }
#pragma unroll
      for (int nsub = 0; nsub < 4; ++nsub)
#pragma unroll
        for (int r = 0; r < 4; ++r)
          Pt[q][(quad << 2) + r][(nsub << 4) + lm] = acc[nsub][r];
    }
    __syncthreads();

    // epilogue: reduce k-split, bias, relu, (+e for stage2), store (512 thr x 2 elems)
    {
      const float2_t p0 = *(const float2_t*)&Pt[0][me][nc];
      const float2_t p1 = *(const float2_t*)&Pt[1][me][nc];
      const float2_t p2 = *(const float2_t*)&Pt[2][me][nc];
      const float2_t p3 = *(const float2_t*)&Pt[3][me][nc];
      const float* bv = st ? b2 : b1;
      const float2_t bias = *(const float2_t*)(bv + n0 + nc);
      float2_t s = p0 + p1 + p2 + p3 + bias;
      s[0] = s[0] > 0.f ? s[0] : 0.f;
      s[1] = s[1] > 0.f ? s[1] : 0.f;
      const int gr = (mt << 4) + me;
      if (!st) {
        u32 o = (u32)f2bf(s[0]) | ((u32)f2bf(s[1]) << 16);
        __hip_atomic_store((u32*)(buf1 + (gr << 10) + n0 + nc), o,
                           __ATOMIC_RELAXED, __HIP_MEMORY_SCOPE_AGENT);
      } else if (t < 255) {
        s[0] += bf2f((u16)(e2 & 0xffffu));
        s[1] += bf2f((u16)(e2 >> 16));
        u32 o = (u32)f2bf(s[0]) | ((u32)f2bf(s[1]) << 16);
        __hip_atomic_store((u32*)(buf0 + (gr << 10) + n0 + nc), o,
                           __ATOMIC_RELAXED, __HIP_MEMORY_SCOPE_AGENT);
      } else {
        *(float2_t*)(fbuf + (gr << 10) + n0 + nc) = s;  // final state; kernel-end flush
      }
    }

    // arrive: drain coherent stores to the coherence point, then relaxed RMW
    if (p < 511) {
      asm volatile("s_waitcnt vmcnt(0)" ::: "memory");
      __syncthreads();
      if (tid == 0)
        __hip_atomic_fetch_add(grp, 1u, __ATOMIC_RELAXED, __HIP_MEMORY_SCOPE_AGENT);
    }
  }
}

__global__ __launch_bounds__(256) void bcast(const float* __restrict__ fbuf,
                                             float* __restrict__ out) {
  const int idx4 = blockIdx.x * 256 + threadIdx.x;   // 0..16777215 float4s
  const int b = idx4 >> 16;
  const int s4 = idx4 & 255;
  const float4_t v = *(const float4_t*)(fbuf + (b << 10) + (s4 << 2));
  *(float4_t*)(out + ((size_t)idx4 << 2)) = v;
}

extern "C" void kernel_launch(void* const* d_in, const int* in_sizes, int n_in,
                              void* d_out, int out_size, void* d_ws, size_t ws_size,
                              hipStream_t stream) {
  const float* x     = (const float*)d_in[0];
  const float* Win   = (const float*)d_in[1];
  const float* bin   = (const float*)d_in[2];
  const float* Wrec  = (const float*)d_in[3];
  const float* brec  = (const float*)d_in[4];
  const float* Wrec2 = (const float*)d_in[5];
  const float* brec2 = (const float*)d_in[6];
  float* out = (float*)d_out;

  char* ws = (char*)d_ws;
  u16* W1b  = (u16*)(ws);                               // 2 MB
  u16* W2b  = (u16*)(ws + (2u << 20));                  // 2 MB
  u16* buf0 = (u16*)(ws + (4u << 20));                  // 512 KB
  u16* buf1 = (u16*)(ws + (4u << 20) + (512u << 10));   // 512 KB
  float* fbuf = (float*)(ws + (5u << 20));              // 1 MB
  u32* cnt  = (u32*)(ws + (6u << 20));                  // 4 KB (16 group counters)
  u16* ebuf = (u16*)d_out;  // 128 MB scratch inside out (268 MB); dead before bcast

  init_counter<<<1, 256, 0, stream>>>(cnt);
  prep_w<<<4096, 256, 0, stream>>>(Wrec, Wrec2, W1b, W2b);
  ext_gemm<<<16384, 256, 0, stream>>>(x, Win, bin, ebuf);

  void* args[] = { (void*)&ebuf, (void*)&buf0, (void*)&buf1, (void*)&W1b, (void*)&W2b,
                   (void*)&brec, (void*)&brec2, (void*)&fbuf, (void*)&cnt };
  (void)hipLaunchCooperativeKernel(reinterpret_cast<void*>(rnn_persistent),
                                   dim3(256), dim3(512), args, 0, stream);

  bcast<<<65536, 256, 0, stream>>>(fbuf, out);
}